// Round 13
// baseline (754.728 us; speedup 1.0000x reference)
//
#include <hip/hip_runtime.h>

#define NN 4096
#define EE 32768
#define ETOT (EE + NN)
#define HH 8
#define KK 4
#define MM 500
#define GG 2000
#define NEGS 0.2f
#define LNEPS 1e-5f

typedef unsigned short ushort;
typedef _Float16 half_t;
typedef __attribute__((ext_vector_type(8))) _Float16 half8;
typedef __attribute__((ext_vector_type(4))) _Float16 half4;
typedef __attribute__((ext_vector_type(4))) float floatx4;

// ---------- helpers ----------

__device__ __forceinline__ void get_edge(const int* __restrict__ ei, int e, int& s, int& d) {
    if (e < EE) { s = ei[e]; d = ei[EE + e]; }
    else        { s = e - EE; d = e - EE; }   // self-loops appended
}

__device__ __forceinline__ half_t f2h(float x) { return (half_t)x; }  // RNE

// async global->LDS, 16 bytes/lane; LDS dest = wave-uniform base + lane*16
__device__ __forceinline__ void async_lds16(const half_t* g, half_t* l) {
    __builtin_amdgcn_global_load_lds(
        (const __attribute__((address_space(1))) unsigned int*)(const void*)g,
        (__attribute__((address_space(3))) unsigned int*)(void*)l,
        16, 0, 0);
}

// ---------- CSR build ----------

__global__ void k_count(const int* __restrict__ ei, int* deg) {
    int e = blockIdx.x * 256 + threadIdx.x;
    if (e < ETOT) { int s, d; get_edge(ei, e, s, d); atomicAdd(&deg[d], 1); }
}

// scan also re-zeroes deg (saves the second memset dispatch)
__global__ void k_scan(int* deg, int* rs, int n) {
    __shared__ int sums[1024];
    int tid = threadIdx.x;
    int base = tid * 4;
    int loc[4]; int s = 0;
    #pragma unroll
    for (int i = 0; i < 4; i++) {
        int v = (base + i < n) ? deg[base + i] : 0;
        loc[i] = s; s += v;
    }
    #pragma unroll
    for (int i = 0; i < 4; i++)
        if (base + i < n) deg[base + i] = 0;
    sums[tid] = s;
    __syncthreads();
    for (int off = 1; off < 1024; off <<= 1) {
        int v = (tid >= off) ? sums[tid - off] : 0;
        __syncthreads();
        sums[tid] += v;
        __syncthreads();
    }
    int prev = (tid > 0) ? sums[tid - 1] : 0;
    #pragma unroll
    for (int i = 0; i < 4; i++)
        if (base + i < n) rs[base + i] = prev + loc[i];
    if (tid == 1023) rs[n] = sums[1023];
}

// fill CSR + convert x to fp16 in one grid (independent work, saves a dispatch)
__global__ void k_fill_f2h(const int* __restrict__ ei, const int* __restrict__ rs,
                           int* cur, int* csr_src,
                           const floatx4* __restrict__ x4, half4* __restrict__ xh4) {
    int i = blockIdx.x * 256 + threadIdx.x;
    if (i < ETOT) {
        int s, d; get_edge(ei, i, s, d);
        int pos = rs[d] + atomicAdd(&cur[d], 1);
        csr_src[pos] = s;
    }
    if (i < NN * 64) {               // NN*256 floats / 4
        floatx4 v = x4[i];
        half4 o;
        o[0] = f2h(v[0]); o[1] = f2h(v[1]); o[2] = f2h(v[2]); o[3] = f2h(v[3]);
        xh4[i] = o;
    }
}

// ---------- layer 1: fold W into attention vectors ----------
// was[h][k] = sum_c W1[k][h*C+c] * as[h][c]  -- one 64-lane wave per (h,k)
// pair with lane-strided coalesced fp32 loads.

__global__ __launch_bounds__(256) void k_wa(const float* __restrict__ W1,
                                            const float* __restrict__ as_,
                                            const float* __restrict__ ad_,
                                            float* was, float* wad, int C, int ldw) {
    int pair = blockIdx.x * 4 + (threadIdx.x >> 6);   // h*256 + k
    int lane = threadIdx.x & 63;
    int h = pair >> 8, k = pair & 255;
    const float* wrow = W1 + (size_t)k * ldw + (size_t)h * C;
    const float* av = as_ + (size_t)h * C;
    const float* bv = ad_ + (size_t)h * C;
    float ss = 0.f, dd = 0.f;
    for (int c = lane; c < C; c += 64) {
        float w = wrow[c];
        ss += w * av[c];
        dd += w * bv[c];
    }
    #pragma unroll
    for (int o = 32; o > 0; o >>= 1) {
        ss += __shfl_down(ss, o, 64);
        dd += __shfl_down(dd, o, 64);
    }
    if (lane == 0) { was[pair] = ss; wad[pair] = dd; }
}

// ---------- layer 1: s,d straight from fp32 x via folded vectors ----------

__global__ __launch_bounds__(256) void k_sd_x(const float* __restrict__ x,
                                              const float* __restrict__ was,
                                              const float* __restrict__ wad,
                                              float* s, float* d) {
    int n = blockIdx.x * 4 + (threadIdx.x >> 6);
    int lane = threadIdx.x & 63;
    const float* xr = x + (size_t)n * 256;
    float x0 = xr[lane], x1 = xr[lane + 64], x2 = xr[lane + 128], x3 = xr[lane + 192];
    #pragma unroll
    for (int h = 0; h < HH; h++) {
        const float* ws = was + h * 256;
        const float* wd = wad + h * 256;
        float ss = x0 * ws[lane] + x1 * ws[lane + 64] + x2 * ws[lane + 128] + x3 * ws[lane + 192];
        float dd = x0 * wd[lane] + x1 * wd[lane + 64] + x2 * wd[lane + 128] + x3 * wd[lane + 192];
        #pragma unroll
        for (int o = 32; o > 0; o >>= 1) {
            ss += __shfl_down(ss, o, 64);
            dd += __shfl_down(dd, o, 64);
        }
        if (lane == 0) { s[n * HH + h] = ss; d[n * HH + h] = dd; }
    }
}

// ---------- layer 1: input-space aggregation: aggx[n][h][256] = sum_e alpha_e,h * x[src] ----------

__global__ __launch_bounds__(256) void k_agg_x(
    const half_t* __restrict__ xh, const float* __restrict__ s, const float* __restrict__ d,
    const int* __restrict__ csr_src, const int* __restrict__ rs,
    half_t* __restrict__ aggx) {
    __shared__ half_t sx[16][256];
    __shared__ int ssrc[16];
    __shared__ float sw[16][HH];
    __shared__ float sh_d[HH];
    __shared__ float sh_z[HH];
    int n = blockIdx.x, tid = threadIdx.x;
    int h = tid >> 5, kc = (tid & 31) * 8;   // thread owns aggx[n][h][kc..kc+8)
    if (tid < HH) { sh_d[tid] = d[(size_t)n * HH + tid]; sh_z[tid] = 0.f; }
    float acc[8];
    #pragma unroll
    for (int e = 0; e < 8; e++) acc[e] = 0.f;
    int start = rs[n], end = rs[n + 1];

    for (int e0 = start; e0 < end; e0 += 16) {
        int cnt = min(16, end - e0);
        if (tid < cnt) ssrc[tid] = csr_src[e0 + tid];
        __syncthreads();                     // ssrc ready; prev iter fully consumed
        for (int q = tid; q < cnt * 32; q += 256) {
            int er = q >> 5, ec = q & 31;
            *((half8*)&sx[er][0] + ec) = *((const half8*)(xh + (size_t)ssrc[er] * 256) + ec);
        }
        if (tid < cnt * HH) {
            int er = tid >> 3, hh = tid & 7;
            float v = s[(size_t)ssrc[er] * HH + hh] + sh_d[hh];
            v = (v >= 0.f) ? v : NEGS * v;   // leaky_relu
            sw[er][hh] = expf(v);
        }
        __syncthreads();                     // sx, sw ready
        if (tid < HH) {
            float zz = 0.f;
            for (int i = 0; i < cnt; i++) zz += sw[i][tid];
            sh_z[tid] += zz;
        }
        for (int i = 0; i < cnt; i++) {
            float w = sw[i][h];
            half8 v = *(const half8*)&sx[i][kc];
            acc[0] += w * (float)v[0]; acc[1] += w * (float)v[1];
            acc[2] += w * (float)v[2]; acc[3] += w * (float)v[3];
            acc[4] += w * (float)v[4]; acc[5] += w * (float)v[5];
            acc[6] += w * (float)v[6]; acc[7] += w * (float)v[7];
        }
    }
    __syncthreads();
    float zi = 1.f / (sh_z[h] + 1e-16f);
    half8 o;
    #pragma unroll
    for (int e = 0; e < 8; e++) o[e] = f2h(acc[e] * zi);
    *(half8*)(aggx + (size_t)n * (HH * 256) + h * 256 + kc) = o;
}

// ---------- layer 1: bias + ReLU + LayerNorm (post-projection) ----------

__global__ __launch_bounds__(256) void k_ln(const half_t* __restrict__ xin,
                                            const float* __restrict__ bias,
                                            const float* __restrict__ gam,
                                            const float* __restrict__ bet,
                                            half_t* __restrict__ outh, int Dout) {
    __shared__ float red[256];
    __shared__ float red2[256];
    int n = blockIdx.x, tid = threadIdx.x;
    int NCH = Dout >> 3;
    float vals[2][8];
    float sum = 0.f, sumsq = 0.f;
    int ai = 0;
    for (int ch = tid; ch < NCH; ch += 256, ai++) {
        half8 v = *(const half8*)(xin + (size_t)n * Dout + (ch << 3));
        #pragma unroll
        for (int e = 0; e < 8; e++) {
            float val = (float)v[e] + bias[(ch << 3) + e];
            val = fmaxf(val, 0.f);
            vals[ai][e] = val;
            sum += val; sumsq += val * val;
        }
    }
    red[tid] = sum; red2[tid] = sumsq;
    __syncthreads();
    for (int o = 128; o > 0; o >>= 1) {
        if (tid < o) { red[tid] += red[tid + o]; red2[tid] += red2[tid + o]; }
        __syncthreads();
    }
    float mu = red[0] / Dout;
    float var = red2[0] / Dout - mu * mu;
    float rstd = rsqrtf(var + LNEPS);
    ai = 0;
    for (int ch = tid; ch < NCH; ch += 256, ai++) {
        half8 o;
        #pragma unroll
        for (int e = 0; e < 8; e++)
            o[e] = f2h((vals[ai][e] - mu) * rstd * gam[(ch << 3) + e] + bet[(ch << 3) + e]);
        *(half8*)(outh + (size_t)n * Dout + (ch << 3)) = o;
    }
}

// ---------- sd body: per-(node,head) attention dots, half4/float4 vectorized ----------

__device__ __forceinline__ void sd_body(const half_t* __restrict__ xp,
                                        const float* __restrict__ as_,
                                        const float* __restrict__ ad_,
                                        float* s, float* d, int H, int C,
                                        int idx, int lane) {
    const half4* row4 = (const half4*)(xp + (size_t)idx * C);
    int h = idx % H;
    const float* av = as_ + (size_t)h * C;
    const float* bv = ad_ + (size_t)h * C;
    int C4 = C >> 2;
    float ss = 0.f, dd = 0.f;
    for (int c4 = lane; c4 < C4; c4 += 64) {
        half4 v = row4[c4];
        floatx4 a = *(const floatx4*)(av + c4 * 4);
        floatx4 b = *(const floatx4*)(bv + c4 * 4);
        float x0 = (float)v[0], x1 = (float)v[1], x2 = (float)v[2], x3 = (float)v[3];
        ss += x0 * a[0] + x1 * a[1] + x2 * a[2] + x3 * a[3];
        dd += x0 * b[0] + x1 * b[1] + x2 * b[2] + x3 * b[3];
    }
    #pragma unroll
    for (int o = 32; o > 0; o >>= 1) {
        ss += __shfl_down(ss, o, 64);
        dd += __shfl_down(dd, o, 64);
    }
    if (lane == 0) { s[idx] = ss; d[idx] = dd; }
}

// standalone sd (head stage tail)
__global__ __launch_bounds__(256) void k_sd4(const half_t* __restrict__ xp,
                                             const float* __restrict__ as_,
                                             const float* __restrict__ ad_,
                                             float* s, float* d, int H, int C, int npairs) {
    int idx = blockIdx.x * 4 + (threadIdx.x >> 6);
    if (idx < npairs)
        sd_body(xp, as_, ad_, s, d, H, C, idx, threadIdx.x & 63);
}

// ---------- fused: sd(stage n) + weight transpose(stage n+1) ----------

__global__ __launch_bounds__(256) void k_sd_wt(
    const half_t* __restrict__ xp, const float* __restrict__ as_,
    const float* __restrict__ ad_, float* s, float* d, int H, int C, int nsd, int npairs,
    const float* __restrict__ W, half_t* __restrict__ Wt,
    int Kd, int Nvalid, int ldw, long long sW, long long sWt, int wgx, int wgy) {
    __shared__ float t[32][33];
    int bid = blockIdx.x;
    if (bid < nsd) {
        int idx = bid * 4 + (threadIdx.x >> 6);
        if (idx < npairs)
            sd_body(xp, as_, ad_, s, d, H, C, idx, threadIdx.x & 63);
        return;
    }
    int wb = bid - nsd;
    int bx = wb % wgx;
    int rem = wb / wgx;
    int by = rem % wgy;
    int bz = rem / wgy;
    const float* Wp = W + (size_t)bz * sW;
    half_t* Wtp = Wt + (size_t)bz * sWt;
    int n0 = bx * 32, k0 = by * 32;
    int tx = threadIdx.x & 31, ty = threadIdx.x >> 5;   // ty 0..7
    #pragma unroll
    for (int i = 0; i < 32; i += 8)
        t[ty + i][tx] = (n0 + tx < Nvalid) ? Wp[(size_t)(k0 + ty + i) * ldw + n0 + tx] : 0.f;
    __syncthreads();
    #pragma unroll
    for (int i = 0; i < 32; i += 8)
        Wtp[(size_t)(n0 + ty + i) * Kd + k0 + tx] = f2h(t[tx][ty + i]);
}

// ---------- weight transpose standalone ----------

__global__ __launch_bounds__(256) void k_wt(const float* __restrict__ W,
                                            half_t* __restrict__ Wt,
                                            int Kd, int Nvalid, int ldw,
                                            long long sW, long long sWt) {
    __shared__ float t[32][33];
    const float* Wp = W + (size_t)blockIdx.z * sW;
    half_t* Wtp = Wt + (size_t)blockIdx.z * sWt;
    int n0 = blockIdx.x * 32, k0 = blockIdx.y * 32;
    int tx = threadIdx.x & 31, ty = threadIdx.x >> 5;   // ty 0..7
    #pragma unroll
    for (int i = 0; i < 32; i += 8)
        t[ty + i][tx] = (n0 + tx < Nvalid) ? Wp[(size_t)(k0 + ty + i) * ldw + n0 + tx] : 0.f;
    __syncthreads();
    #pragma unroll
    for (int i = 0; i < 32; i += 8)
        Wtp[(size_t)(n0 + ty + i) * Kd + k0 + tx] = f2h(t[tx][ty + i]);
}

// ---------- fp16 MFMA GEMM: Ch[M][ldc] = A[M][lda-strided] * Bt[Npad][Kd]^T ----------
// 128x128 tile, BK=64, XOR-swizzled LDS chunks.  [proven: 108us on L2 shape]

#define BM 128
#define BN 128
#define BK 64

__global__ __launch_bounds__(256) void k_gemm_mfma(
    const half_t* __restrict__ A,    // [M][lda] fp16
    const half_t* __restrict__ Bt,   // [Npad][Kd] fp16 (B transposed)
    half_t* __restrict__ C,          // fp16 output
    int Kd, int lda, int Nreal, int ldc,
    long long strideA, long long strideBt, long long strideC)
{
    __shared__ __align__(16) half_t As[BM * BK];
    __shared__ __align__(16) half_t Bs[BN * BK];

    const half_t* Ap  = A  + (size_t)blockIdx.z * strideA;
    const half_t* Btp = Bt + (size_t)blockIdx.z * strideBt;
    half_t* Cp = C + (size_t)blockIdx.z * strideC;
    int col0 = blockIdx.x * BN, row0 = blockIdx.y * BM;

    int lane = threadIdx.x & 63;
    int wave = threadIdx.x >> 6;
    int wm = (wave >> 1) * 64, wn = (wave & 1) * 64;

    int srow = wave * 32 + (lane >> 3);
    int gchunk = (lane & 7) ^ ((lane >> 3) & 7);     // (srow&7) == (lane>>3)&7
    const half_t* ga = Ap  + (size_t)(row0 + srow) * lda + gchunk * 8;
    const half_t* gb = Btp + (size_t)(col0 + srow) * Kd + gchunk * 8;
    half_t* lA = &As[(wave * 32) * BK];
    half_t* lB = &Bs[(wave * 32) * BK];

    int r = lane & 15;
    int rx = r & 7;

    floatx4 acc[4][4];
    #pragma unroll
    for (int i = 0; i < 4; i++)
        #pragma unroll
        for (int j = 0; j < 4; j++) acc[i][j] = (floatx4){0.f, 0.f, 0.f, 0.f};

    for (int k0 = 0; k0 < Kd; k0 += BK) {
        #pragma unroll
        for (int j = 0; j < 4; j++) {
            async_lds16(ga + k0 + (size_t)(j * 8) * lda, lA + (j * 8) * BK);
            async_lds16(gb + k0 + (size_t)(j * 8) * Kd, lB + (j * 8) * BK);
        }
        __syncthreads();
        #pragma unroll
        for (int kk = 0; kk < BK; kk += 32) {
            int phys = (((kk >> 3) + (lane >> 4)) ^ rx) << 3;
            half8 a[4], b[4];
            #pragma unroll
            for (int i = 0; i < 4; i++)
                a[i] = *(const half8*)&As[(wm + i * 16 + r) * BK + phys];
            #pragma unroll
            for (int j = 0; j < 4; j++)
                b[j] = *(const half8*)&Bs[(wn + j * 16 + r) * BK + phys];
            #pragma unroll
            for (int i = 0; i < 4; i++)
                #pragma unroll
                for (int j = 0; j < 4; j++)
                    acc[i][j] = __builtin_amdgcn_mfma_f32_16x16x32_f16(a[i], b[j], acc[i][j], 0, 0, 0);
        }
        __syncthreads();
    }

    int q4 = (lane >> 4) * 4;
    #pragma unroll
    for (int i = 0; i < 4; i++) {
        #pragma unroll
        for (int rr = 0; rr < 4; rr++) {
            int row = row0 + wm + i * 16 + q4 + rr;
            #pragma unroll
            for (int j = 0; j < 4; j++) {
                int col = col0 + wn + j * 16 + (lane & 15);
                if (col < Nreal) Cp[(size_t)row * ldc + col] = f2h(acc[i][j][rr]);
            }
        }
    }
}

// ---------- aggregation + softmax + ReLU + LayerNorm fused (layers 2,3) ----------

__global__ __launch_bounds__(256) void k_agg_ln(
    const half_t* __restrict__ xp, const float* __restrict__ s, const float* __restrict__ d,
    const int* __restrict__ csr_src, const int* __restrict__ rs,
    const float* __restrict__ bias, const float* __restrict__ gam,
    const float* __restrict__ bet, half_t* __restrict__ outh, int H, int C) {
    __shared__ int sh_src[256];
    __shared__ float sh_w[256 * HH];
    __shared__ float sh_d[HH];
    __shared__ float sh_z[HH];
    __shared__ float red[256];
    __shared__ float red2[256];
    int n = blockIdx.x, tid = threadIdx.x;
    int Dout = H * C;
    int NCH = Dout >> 3;
    int CCH = C >> 3;
    int start = rs[n], end = rs[n + 1];
    if (tid < H) { sh_d[tid] = d[(size_t)n * H + tid]; sh_z[tid] = 0.f; }
    float acc[2][8];
    #pragma unroll
    for (int a = 0; a < 2; a++)
        #pragma unroll
        for (int e = 0; e < 8; e++) acc[a][e] = 0.f;

    for (int e0 = start; e0 < end; e0 += 256) {
        int cnt = min(256, end - e0);
        if (tid < cnt) sh_src[tid] = csr_src[e0 + tid];
        __syncthreads();
        for (int i = tid; i < cnt * H; i += 256) {
            int ei = i / H, h = i - ei * H;
            float v = s[(size_t)sh_src[ei] * H + h] + sh_d[h];
            v = (v >= 0.f) ? v : NEGS * v;   // leaky_relu
            sh_w[i] = expf(v);
        }
        __syncthreads();
        if (tid < H) {
            float zz = 0.f;
            for (int i = 0; i < cnt; i++) zz += sh_w[i * H + tid];
            sh_z[tid] += zz;
        }
        int ai = 0;
        for (int ch = tid; ch < NCH; ch += 256, ai++) {
            int h = ch / CCH;
            float a0 = acc[ai][0], a1 = acc[ai][1], a2 = acc[ai][2], a3 = acc[ai][3];
            float a4 = acc[ai][4], a5 = acc[ai][5], a6 = acc[ai][6], a7 = acc[ai][7];
            for (int i = 0; i < cnt; i++) {
                float w = sh_w[i * H + h];
                half8 v = *(const half8*)(xp + (size_t)sh_src[i] * Dout + (ch << 3));
                a0 += w * (float)v[0]; a1 += w * (float)v[1];
                a2 += w * (float)v[2]; a3 += w * (float)v[3];
                a4 += w * (float)v[4]; a5 += w * (float)v[5];
                a6 += w * (float)v[6]; a7 += w * (float)v[7];
            }
            acc[ai][0] = a0; acc[ai][1] = a1; acc[ai][2] = a2; acc[ai][3] = a3;
            acc[ai][4] = a4; acc[ai][5] = a5; acc[ai][6] = a6; acc[ai][7] = a7;
        }
        __syncthreads();
    }

    float vals[2][8];
    float sum = 0.f, sumsq = 0.f;
    int ai = 0;
    for (int ch = tid; ch < NCH; ch += 256, ai++) {
        int h = ch / CCH;
        float zi = 1.f / (sh_z[h] + 1e-16f);
        #pragma unroll
        for (int e = 0; e < 8; e++) {
            float v = acc[ai][e] * zi + bias[(ch << 3) + e];
            v = fmaxf(v, 0.f);
            vals[ai][e] = v;
            sum += v; sumsq += v * v;
        }
    }
    red[tid] = sum; red2[tid] = sumsq;
    __syncthreads();
    for (int o = 128; o > 0; o >>= 1) {
        if (tid < o) { red[tid] += red[tid + o]; red2[tid] += red2[tid + o]; }
        __syncthreads();
    }
    float mu = red[0] / Dout;
    float var = red2[0] / Dout - mu * mu;
    float rstd = rsqrtf(var + LNEPS);
    ai = 0;
    for (int ch = tid; ch < NCH; ch += 256, ai++) {
        half8 o;
        #pragma unroll
        for (int e = 0; e < 8; e++)
            o[e] = f2h((vals[ai][e] - mu) * rstd * gam[(ch << 3) + e] + bet[(ch << 3) + e]);
        *(half8*)(outh + (size_t)n * Dout + (ch << 3)) = o;
    }
}

// ---------- head aggregation (fused softmax), writes per_head and scattered full ----------

__global__ __launch_bounds__(256) void k_agg_head(
    const half_t* __restrict__ xp, const float* __restrict__ s, const float* __restrict__ d,
    const int* __restrict__ csr_src, const int* __restrict__ rs,
    const float* __restrict__ bias, const int* __restrict__ idxm,
    float* out_full, float* out_ph) {
    __shared__ int sh_src[256];
    __shared__ float sh_w[256 * KK];
    __shared__ float sh_d[KK];
    __shared__ float sh_z[KK];
    int n = blockIdx.x, tid = threadIdx.x;
    const int Dout = KK * MM;        // 2000
    const int NCH = Dout >> 3;       // 250 chunks; threads 250..255 idle
    int start = rs[n], end = rs[n + 1];
    if (tid < KK) { sh_d[tid] = d[(size_t)n * KK + tid]; sh_z[tid] = 0.f; }
    float acc[8];
    #pragma unroll
    for (int e = 0; e < 8; e++) acc[e] = 0.f;
    int ch = tid;
    int cb = ch << 3;

    for (int e0 = start; e0 < end; e0 += 256) {
        int cnt = min(256, end - e0);
        if (tid < cnt) sh_src[tid] = csr_src[e0 + tid];
        __syncthreads();
        for (int i = tid; i < cnt * KK; i += 256) {
            int ei = i / KK, k = i - ei * KK;
            float v = s[(size_t)sh_src[ei] * KK + k] + sh_d[k];
            v = (v >= 0.f) ? v : NEGS * v;
            sh_w[i] = expf(v);
        }
        __syncthreads();
        if (tid < KK) {
            float zz = 0.f;
            for (int i = 0; i < cnt; i++) zz += sh_w[i * KK + tid];
            sh_z[tid] += zz;
        }
        if (ch < NCH) {
            for (int i = 0; i < cnt; i++) {
                const float* wv = &sh_w[i * KK];
                half8 v = *(const half8*)(xp + (size_t)sh_src[i] * Dout + cb);
                #pragma unroll
                for (int e = 0; e < 8; e++)
                    acc[e] += wv[(cb + e) / MM] * (float)v[e];
            }
        }
        __syncthreads();
    }
    if (ch < NCH) {
        #pragma unroll
        for (int e = 0; e < 8; e++) {
            int c = cb + e;
            int k = c / MM, m = c - k * MM;
            float v = acc[e] / (sh_z[k] + 1e-16f) + bias[c];
            out_ph[((size_t)k * NN + n) * MM + m] = v;
            out_full[(size_t)n * GG + idxm[c]] = v;
        }
    }
}

// ---------- host launcher ----------
// DIAGNOSTIC ROUND: the four aggregation dispatches are each launched TWICE
// (idempotent: none reads its own output). dur_us inflation vs R12 at equal
// GEMM-clock == total agg execution time + 4 launch gaps. Outputs bit-identical.

extern "C" void kernel_launch(void* const* d_in, const int* in_sizes, int n_in,
                              void* d_out, int out_size, void* d_ws, size_t ws_size,
                              hipStream_t stream) {
    (void)in_sizes; (void)n_in; (void)out_size; (void)ws_size;
    const float* x   = (const float*)d_in[0];
    const int*   ei  = (const int*)d_in[1];
    const float* W1  = (const float*)d_in[2];
    const float* as1 = (const float*)d_in[3];
    const float* ad1 = (const float*)d_in[4];
    const float* b1  = (const float*)d_in[5];
    const float* g1  = (const float*)d_in[6];
    const float* be1 = (const float*)d_in[7];
    const float* W2  = (const float*)d_in[8];
    const float* as2 = (const float*)d_in[9];
    const float* ad2 = (const float*)d_in[10];
    const float* b2  = (const float*)d_in[11];
    const float* g2  = (const float*)d_in[12];
    const float* be2 = (const float*)d_in[13];
    const float* W3  = (const float*)d_in[14];
    const float* as3 = (const float*)d_in[15];
    const float* ad3 = (const float*)d_in[16];
    const float* b3  = (const float*)d_in[17];
    const float* g3  = (const float*)d_in[18];
    const float* be3 = (const float*)d_in[19];
    const float* Wh  = (const float*)d_in[20];
    const float* ash = (const float*)d_in[21];
    const float* adh = (const float*)d_in[22];
    const float* bh  = (const float*)d_in[23];
    const int*   idxm = (const int*)d_in[24];
    float* out = (float*)d_out;

    // workspace carve (~54 MB)
    char* w = (char*)d_ws;
    auto carve = [&](size_t bytes) { char* p = w; w += (bytes + 255) & ~(size_t)255; return p; };
    half_t* xp16    = (half_t*)carve((size_t)NN * 3584 * 2);           // GEMM output (fp16)
    half_t* Wt      = (half_t*)carve((size_t)12100000 * 2);            // fp16 weights, two regions
    float*  sarr    = (float*)carve((size_t)NN * HH * 4);
    float*  darr    = (float*)carve((size_t)NN * HH * 4);
    float*  was     = (float*)carve((size_t)HH * 256 * 4);
    float*  wad     = (float*)carve((size_t)HH * 256 * 4);
    int*    csr_src = (int*)carve((size_t)ETOT * 4);
    int*    rowst   = (int*)carve((size_t)(NN + 1) * 4);
    int*    cur     = (int*)carve((size_t)NN * 4);
    half_t* Ah   = (half_t*)d_out;
    half_t* aggx = (half_t*)(out + (size_t)NN * GG);
    half_t* Wt2  = Wt + (size_t)1048576;     // second weight region

    // ---- CSR build + x->fp16 ----
    hipMemsetAsync(cur, 0, (size_t)NN * 4, stream);
    k_count<<<(ETOT + 255) / 256, 256, 0, stream>>>(ei, cur);
    k_scan<<<1, 1024, 0, stream>>>(cur, rowst, NN);          // also re-zeroes cur
    k_fill_f2h<<<(NN * 64 + 255) / 256, 256, 0, stream>>>(
        ei, rowst, cur, csr_src, (const floatx4*)x, (half4*)Ah);

    // ---- layer 1 (input-space aggregation) ----
    k_wa<<<(HH * 256) / 4, 256, 0, stream>>>(W1, as1, ad1, was, wad, 448, 3584);
    k_wt<<<dim3(3584 / 32, 256 / 32, 1), 256, 0, stream>>>(W1, Wt, 256, 3584, 3584, 0, 0);
    k_sd_x<<<NN / 4, 256, 0, stream>>>(x, was, wad, sarr, darr);
    k_agg_x<<<NN, 256, 0, stream>>>(Ah, sarr, darr, csr_src, rowst, aggx);   // DIAG dup
    k_agg_x<<<NN, 256, 0, stream>>>(Ah, sarr, darr, csr_src, rowst, aggx);
    k_gemm_mfma<<<dim3(4, NN / BM, HH), 256, 0, stream>>>(
        aggx, Wt, xp16, 256, HH * 256, 448, 3584,
        256LL, (long long)448 * 256, 448LL);
    k_ln<<<NN, 256, 0, stream>>>(xp16, b1, g1, be1, Ah, 3584);

    // ---- layer 2 ----
    k_wt<<<dim3(3072 / 32, 3584 / 32, 1), 256, 0, stream>>>(W2, Wt2, 3584, 3072, 3072, 0, 0);
    k_gemm_mfma<<<dim3(3072 / BN, NN / BM, 1), 256, 0, stream>>>(
        Ah, Wt2, xp16, 3584, 3584, 3072, 3072, 0, 0, 0);
    k_sd_wt<<<8192 + 6144, 256, 0, stream>>>(
        xp16, as2, ad2, sarr, darr, HH, 384, 8192, NN * HH,
        W3, Wt, 3072, 2048, 2048, 0, 0, 64, 96);
    k_agg_ln<<<NN, 256, 0, stream>>>(xp16, sarr, darr, csr_src, rowst,       // DIAG dup
                                     b2, g2, be2, Ah, HH, 384);
    k_agg_ln<<<NN, 256, 0, stream>>>(xp16, sarr, darr, csr_src, rowst,
                                     b2, g2, be2, Ah, HH, 384);

    // ---- layer 3 ----
    k_gemm_mfma<<<dim3(2048 / BN, NN / BM, 1), 256, 0, stream>>>(
        Ah, Wt, xp16, 3072, 3072, 2048, 2048, 0, 0, 0);
    k_sd_wt<<<8192 + 4096, 256, 0, stream>>>(
        xp16, as3, ad3, sarr, darr, HH, 256, 8192, NN * HH,
        Wh, Wt, 2048, MM, MM, (long long)2048 * MM, (long long)512 * 2048, 16, 64);
    k_agg_ln<<<NN, 256, 0, stream>>>(xp16, sarr, darr, csr_src, rowst,       // DIAG dup
                                     b3, g3, be3, Ah, HH, 256);
    k_agg_ln<<<NN, 256, 0, stream>>>(xp16, sarr, darr, csr_src, rowst,
                                     b3, g3, be3, Ah, HH, 256);

    // ---- head stage ----
    k_gemm_mfma<<<dim3(512 / BN, NN / BM, KK), 256, 0, stream>>>(
        Ah, Wt, xp16, 2048, 2048, MM, GG, 0, (long long)512 * 2048, (long long)MM);
    k_sd4<<<(NN * KK) / 4, 256, 0, stream>>>(xp16, ash, adh, sarr, darr, KK, MM, NN * KK);
    k_agg_head<<<NN, 256, 0, stream>>>(xp16, sarr, darr, csr_src, rowst,     // DIAG dup
                                       bh, idxm, out, out + (size_t)NN * GG);
    k_agg_head<<<NN, 256, 0, stream>>>(xp16, sarr, darr, csr_src, rowst,
                                       bh, idxm, out, out + (size_t)NN * GG);
}

// Round 14
// 607.258 us; speedup vs baseline: 1.2428x; 1.2428x over previous
//
#include <hip/hip_runtime.h>

#define NN 4096
#define EE 32768
#define ETOT (EE + NN)
#define HH 8
#define KK 4
#define MM 500
#define GG 2000
#define NEGS 0.2f
#define LNEPS 1e-5f

typedef unsigned short ushort;
typedef _Float16 half_t;
typedef __attribute__((ext_vector_type(8))) _Float16 half8;
typedef __attribute__((ext_vector_type(4))) _Float16 half4;
typedef __attribute__((ext_vector_type(4))) float floatx4;

// ---------- helpers ----------

__device__ __forceinline__ void get_edge(const int* __restrict__ ei, int e, int& s, int& d) {
    if (e < EE) { s = ei[e]; d = ei[EE + e]; }
    else        { s = e - EE; d = e - EE; }   // self-loops appended
}

__device__ __forceinline__ half_t f2h(float x) { return (half_t)x; }  // RNE

// async global->LDS, 16 bytes/lane; LDS dest = wave-uniform base + lane*16
__device__ __forceinline__ void async_lds16(const half_t* g, half_t* l) {
    __builtin_amdgcn_global_load_lds(
        (const __attribute__((address_space(1))) unsigned int*)(const void*)g,
        (__attribute__((address_space(3))) unsigned int*)(void*)l,
        16, 0, 0);
}

// ---------- CSR build ----------

__global__ void k_count(const int* __restrict__ ei, int* deg) {
    int e = blockIdx.x * 256 + threadIdx.x;
    if (e < ETOT) { int s, d; get_edge(ei, e, s, d); atomicAdd(&deg[d], 1); }
}

// scan also re-zeroes deg (saves the second memset dispatch)
__global__ void k_scan(int* deg, int* rs, int n) {
    __shared__ int sums[1024];
    int tid = threadIdx.x;
    int base = tid * 4;
    int loc[4]; int s = 0;
    #pragma unroll
    for (int i = 0; i < 4; i++) {
        int v = (base + i < n) ? deg[base + i] : 0;
        loc[i] = s; s += v;
    }
    #pragma unroll
    for (int i = 0; i < 4; i++)
        if (base + i < n) deg[base + i] = 0;
    sums[tid] = s;
    __syncthreads();
    for (int off = 1; off < 1024; off <<= 1) {
        int v = (tid >= off) ? sums[tid - off] : 0;
        __syncthreads();
        sums[tid] += v;
        __syncthreads();
    }
    int prev = (tid > 0) ? sums[tid - 1] : 0;
    #pragma unroll
    for (int i = 0; i < 4; i++)
        if (base + i < n) rs[base + i] = prev + loc[i];
    if (tid == 1023) rs[n] = sums[1023];
}

// ---------- fused: wa (fold W1 into attention vecs) + wt1 (W1 transpose) ----------
// wa: was[h*256+k] = sum_c W1[k][h*448+c]*as[h][c]; one 64-lane wave per pair.
// wt1: W1[256][3584] fp32 -> Wt[3584][256] fp16.  Independent, role-split.

#define NWA 512          // (HH*256)/4 wa blocks
#define WT1X 112         // 3584/32
__global__ __launch_bounds__(256) void k_wa_wt1(
    const float* __restrict__ W1, const float* __restrict__ as_,
    const float* __restrict__ ad_, float* was, float* wad,
    half_t* __restrict__ Wt) {
    __shared__ float t[32][33];
    int bid = blockIdx.x;
    if (bid < NWA) {
        int pair = bid * 4 + (threadIdx.x >> 6);   // h*256 + k
        int lane = threadIdx.x & 63;
        int h = pair >> 8, k = pair & 255;
        const float* wrow = W1 + (size_t)k * 3584 + (size_t)h * 448;
        const float* av = as_ + (size_t)h * 448;
        const float* bv = ad_ + (size_t)h * 448;
        float ss = 0.f, dd = 0.f;
        for (int c = lane; c < 448; c += 64) {
            float w = wrow[c];
            ss += w * av[c];
            dd += w * bv[c];
        }
        #pragma unroll
        for (int o = 32; o > 0; o >>= 1) {
            ss += __shfl_down(ss, o, 64);
            dd += __shfl_down(dd, o, 64);
        }
        if (lane == 0) { was[pair] = ss; wad[pair] = dd; }
        return;
    }
    int wb = bid - NWA;
    int bx = wb % WT1X, by = wb / WT1X;
    int n0 = bx * 32, k0 = by * 32;
    int tx = threadIdx.x & 31, ty = threadIdx.x >> 5;
    #pragma unroll
    for (int i = 0; i < 32; i += 8)
        t[ty + i][tx] = W1[(size_t)(k0 + ty + i) * 3584 + n0 + tx];
    __syncthreads();
    #pragma unroll
    for (int i = 0; i < 32; i += 8)
        Wt[(size_t)(n0 + ty + i) * 256 + k0 + tx] = f2h(t[tx][ty + i]);
}

// ---------- fused: CSR fill + x->fp16 + layer-1 s,d from folded vectors ----------
// Blocks [0,1024): fill (i<ETOT) + f2h (i<NN*64).  Blocks [1024,2048): sd_x.

__global__ __launch_bounds__(256) void k_fill_f2h_sdx(
    const int* __restrict__ ei, const int* __restrict__ rs, int* cur, int* csr_src,
    const floatx4* __restrict__ x4, half4* __restrict__ xh4,
    const float* __restrict__ x, const float* __restrict__ was,
    const float* __restrict__ wad, float* s, float* d) {
    int bid = blockIdx.x;
    if (bid < 1024) {
        int i = bid * 256 + threadIdx.x;
        if (i < ETOT) {
            int ss, dd; get_edge(ei, i, ss, dd);
            int pos = rs[dd] + atomicAdd(&cur[dd], 1);
            csr_src[pos] = ss;
        }
        if (i < NN * 64) {
            floatx4 v = x4[i];
            half4 o;
            o[0] = f2h(v[0]); o[1] = f2h(v[1]); o[2] = f2h(v[2]); o[3] = f2h(v[3]);
            xh4[i] = o;
        }
        return;
    }
    int n = (bid - 1024) * 4 + (threadIdx.x >> 6);
    int lane = threadIdx.x & 63;
    const float* xr = x + (size_t)n * 256;
    float x0 = xr[lane], x1 = xr[lane + 64], x2 = xr[lane + 128], x3 = xr[lane + 192];
    #pragma unroll
    for (int h = 0; h < HH; h++) {
        const float* ws = was + h * 256;
        const float* wd = wad + h * 256;
        float ss = x0 * ws[lane] + x1 * ws[lane + 64] + x2 * ws[lane + 128] + x3 * ws[lane + 192];
        float dd = x0 * wd[lane] + x1 * wd[lane + 64] + x2 * wd[lane + 128] + x3 * wd[lane + 192];
        #pragma unroll
        for (int o = 32; o > 0; o >>= 1) {
            ss += __shfl_down(ss, o, 64);
            dd += __shfl_down(dd, o, 64);
        }
        if (lane == 0) { s[n * HH + h] = ss; d[n * HH + h] = dd; }
    }
}

// ---------- layer 1: input-space aggregation: aggx[n][h][256] = sum_e alpha_e,h * x[src] ----------

__global__ __launch_bounds__(256) void k_agg_x(
    const half_t* __restrict__ xh, const float* __restrict__ s, const float* __restrict__ d,
    const int* __restrict__ csr_src, const int* __restrict__ rs,
    half_t* __restrict__ aggx) {
    __shared__ half_t sx[16][256];
    __shared__ int ssrc[16];
    __shared__ float sw[16][HH];
    __shared__ float sh_d[HH];
    __shared__ float sh_z[HH];
    int n = blockIdx.x, tid = threadIdx.x;
    int h = tid >> 5, kc = (tid & 31) * 8;   // thread owns aggx[n][h][kc..kc+8)
    if (tid < HH) { sh_d[tid] = d[(size_t)n * HH + tid]; sh_z[tid] = 0.f; }
    float acc[8];
    #pragma unroll
    for (int e = 0; e < 8; e++) acc[e] = 0.f;
    int start = rs[n], end = rs[n + 1];

    for (int e0 = start; e0 < end; e0 += 16) {
        int cnt = min(16, end - e0);
        if (tid < cnt) ssrc[tid] = csr_src[e0 + tid];
        __syncthreads();                     // ssrc ready; prev iter fully consumed
        for (int q = tid; q < cnt * 32; q += 256) {
            int er = q >> 5, ec = q & 31;
            *((half8*)&sx[er][0] + ec) = *((const half8*)(xh + (size_t)ssrc[er] * 256) + ec);
        }
        if (tid < cnt * HH) {
            int er = tid >> 3, hh = tid & 7;
            float v = s[(size_t)ssrc[er] * HH + hh] + sh_d[hh];
            v = (v >= 0.f) ? v : NEGS * v;   // leaky_relu
            sw[er][hh] = expf(v);
        }
        __syncthreads();                     // sx, sw ready
        if (tid < HH) {
            float zz = 0.f;
            for (int i = 0; i < cnt; i++) zz += sw[i][tid];
            sh_z[tid] += zz;
        }
        for (int i = 0; i < cnt; i++) {
            float w = sw[i][h];
            half8 v = *(const half8*)&sx[i][kc];
            acc[0] += w * (float)v[0]; acc[1] += w * (float)v[1];
            acc[2] += w * (float)v[2]; acc[3] += w * (float)v[3];
            acc[4] += w * (float)v[4]; acc[5] += w * (float)v[5];
            acc[6] += w * (float)v[6]; acc[7] += w * (float)v[7];
        }
    }
    __syncthreads();
    float zi = 1.f / (sh_z[h] + 1e-16f);
    half8 o;
    #pragma unroll
    for (int e = 0; e < 8; e++) o[e] = f2h(acc[e] * zi);
    *(half8*)(aggx + (size_t)n * (HH * 256) + h * 256 + kc) = o;
}

// ---------- fused: layer-1 bias+ReLU+LN + wt2 (W2 transpose) ----------
// Blocks [0,NN): ln over xin rows (Dout=3584). Blocks [NN, NN+10752): wt2
// W2[3584][3072] fp32 -> Wt2[3072][3584] fp16.  Independent, role-split.

#define WT2X 96          // 3072/32
__global__ __launch_bounds__(256) void k_ln_wt2(
    const half_t* __restrict__ xin, const float* __restrict__ bias,
    const float* __restrict__ gam, const float* __restrict__ bet,
    half_t* __restrict__ outh,
    const float* __restrict__ W2, half_t* __restrict__ Wt2) {
    __shared__ float t[32][33];
    __shared__ float red[256];
    __shared__ float red2[256];
    int bid = blockIdx.x, tid = threadIdx.x;
    if (bid >= NN) {
        int wb = bid - NN;
        int bx = wb % WT2X, by = wb / WT2X;
        int n0 = bx * 32, k0 = by * 32;
        int tx = tid & 31, ty = tid >> 5;
        #pragma unroll
        for (int i = 0; i < 32; i += 8)
            t[ty + i][tx] = W2[(size_t)(k0 + ty + i) * 3072 + n0 + tx];
        __syncthreads();
        #pragma unroll
        for (int i = 0; i < 32; i += 8)
            Wt2[(size_t)(n0 + ty + i) * 3584 + k0 + tx] = f2h(t[tx][ty + i]);
        return;
    }
    const int Dout = 3584;
    const int NCH = Dout >> 3;
    int n = bid;
    float vals[2][8];
    float sum = 0.f, sumsq = 0.f;
    int ai = 0;
    for (int ch = tid; ch < NCH; ch += 256, ai++) {
        half8 v = *(const half8*)(xin + (size_t)n * Dout + (ch << 3));
        #pragma unroll
        for (int e = 0; e < 8; e++) {
            float val = (float)v[e] + bias[(ch << 3) + e];
            val = fmaxf(val, 0.f);
            vals[ai][e] = val;
            sum += val; sumsq += val * val;
        }
    }
    red[tid] = sum; red2[tid] = sumsq;
    __syncthreads();
    for (int o = 128; o > 0; o >>= 1) {
        if (tid < o) { red[tid] += red[tid + o]; red2[tid] += red2[tid + o]; }
        __syncthreads();
    }
    float mu = red[0] / Dout;
    float var = red2[0] / Dout - mu * mu;
    float rstd = rsqrtf(var + LNEPS);
    ai = 0;
    for (int ch = tid; ch < NCH; ch += 256, ai++) {
        half8 o;
        #pragma unroll
        for (int e = 0; e < 8; e++)
            o[e] = f2h((vals[ai][e] - mu) * rstd * gam[(ch << 3) + e] + bet[(ch << 3) + e]);
        *(half8*)(outh + (size_t)n * Dout + (ch << 3)) = o;
    }
}

// ---------- sd body: per-(node,head) attention dots, half4/float4 vectorized ----------

__device__ __forceinline__ void sd_body(const half_t* __restrict__ xp,
                                        const float* __restrict__ as_,
                                        const float* __restrict__ ad_,
                                        float* s, float* d, int H, int C,
                                        int idx, int lane) {
    const half4* row4 = (const half4*)(xp + (size_t)idx * C);
    int h = idx % H;
    const float* av = as_ + (size_t)h * C;
    const float* bv = ad_ + (size_t)h * C;
    int C4 = C >> 2;
    float ss = 0.f, dd = 0.f;
    for (int c4 = lane; c4 < C4; c4 += 64) {
        half4 v = row4[c4];
        floatx4 a = *(const floatx4*)(av + c4 * 4);
        floatx4 b = *(const floatx4*)(bv + c4 * 4);
        float x0 = (float)v[0], x1 = (float)v[1], x2 = (float)v[2], x3 = (float)v[3];
        ss += x0 * a[0] + x1 * a[1] + x2 * a[2] + x3 * a[3];
        dd += x0 * b[0] + x1 * b[1] + x2 * b[2] + x3 * b[3];
    }
    #pragma unroll
    for (int o = 32; o > 0; o >>= 1) {
        ss += __shfl_down(ss, o, 64);
        dd += __shfl_down(dd, o, 64);
    }
    if (lane == 0) { s[idx] = ss; d[idx] = dd; }
}

// standalone sd (head stage tail)
__global__ __launch_bounds__(256) void k_sd4(const half_t* __restrict__ xp,
                                             const float* __restrict__ as_,
                                             const float* __restrict__ ad_,
                                             float* s, float* d, int H, int C, int npairs) {
    int idx = blockIdx.x * 4 + (threadIdx.x >> 6);
    if (idx < npairs)
        sd_body(xp, as_, ad_, s, d, H, C, idx, threadIdx.x & 63);
}

// ---------- fused: sd(stage n) + weight transpose(stage n+1) ----------

__global__ __launch_bounds__(256) void k_sd_wt(
    const half_t* __restrict__ xp, const float* __restrict__ as_,
    const float* __restrict__ ad_, float* s, float* d, int H, int C, int nsd, int npairs,
    const float* __restrict__ W, half_t* __restrict__ Wt,
    int Kd, int Nvalid, int ldw, long long sW, long long sWt, int wgx, int wgy) {
    __shared__ float t[32][33];
    int bid = blockIdx.x;
    if (bid < nsd) {
        int idx = bid * 4 + (threadIdx.x >> 6);
        if (idx < npairs)
            sd_body(xp, as_, ad_, s, d, H, C, idx, threadIdx.x & 63);
        return;
    }
    int wb = bid - nsd;
    int bx = wb % wgx;
    int rem = wb / wgx;
    int by = rem % wgy;
    int bz = rem / wgy;
    const float* Wp = W + (size_t)bz * sW;
    half_t* Wtp = Wt + (size_t)bz * sWt;
    int n0 = bx * 32, k0 = by * 32;
    int tx = threadIdx.x & 31, ty = threadIdx.x >> 5;   // ty 0..7
    #pragma unroll
    for (int i = 0; i < 32; i += 8)
        t[ty + i][tx] = (n0 + tx < Nvalid) ? Wp[(size_t)(k0 + ty + i) * ldw + n0 + tx] : 0.f;
    __syncthreads();
    #pragma unroll
    for (int i = 0; i < 32; i += 8)
        Wtp[(size_t)(n0 + ty + i) * Kd + k0 + tx] = f2h(t[tx][ty + i]);
}

// ---------- fp16 MFMA GEMM: Ch[M][ldc] = A[M][lda-strided] * Bt[Npad][Kd]^T ----------
// 128x128 tile, BK=64, XOR-swizzled LDS chunks.  [proven: 108us on L2 shape]
// XCD-chunked block swizzle (T1): consecutive dispatch slots round-robin
// across 8 XCDs; remap so each XCD gets a contiguous chunk of (by,bx) space
// -> each XCD's L2 holds few A-row panels instead of all of them.
// Requires gridDim.x*gridDim.y % 8 == 0 (all our launches); else identity.

#define BM 128
#define BN 128
#define BK 64

__global__ __launch_bounds__(256) void k_gemm_mfma(
    const half_t* __restrict__ A,    // [M][lda] fp16
    const half_t* __restrict__ Bt,   // [Npad][Kd] fp16 (B transposed)
    half_t* __restrict__ C,          // fp16 output
    int Kd, int lda, int Nreal, int ldc,
    long long strideA, long long strideBt, long long strideC)
{
    __shared__ __align__(16) half_t As[BM * BK];
    __shared__ __align__(16) half_t Bs[BN * BK];

    const half_t* Ap  = A  + (size_t)blockIdx.z * strideA;
    const half_t* Btp = Bt + (size_t)blockIdx.z * strideBt;
    half_t* Cp = C + (size_t)blockIdx.z * strideC;

    int bx = blockIdx.x, by = blockIdx.y;
    int nb = gridDim.x * gridDim.y;
    if ((nb & 7) == 0) {
        int bid = by * gridDim.x + bx;
        int nper = nb >> 3;
        int swz = (bid & 7) * nper + (bid >> 3);
        bx = swz % gridDim.x;
        by = swz / gridDim.x;
    }
    int col0 = bx * BN, row0 = by * BM;

    int lane = threadIdx.x & 63;
    int wave = threadIdx.x >> 6;
    int wm = (wave >> 1) * 64, wn = (wave & 1) * 64;

    int srow = wave * 32 + (lane >> 3);
    int gchunk = (lane & 7) ^ ((lane >> 3) & 7);     // (srow&7) == (lane>>3)&7
    const half_t* ga = Ap  + (size_t)(row0 + srow) * lda + gchunk * 8;
    const half_t* gb = Btp + (size_t)(col0 + srow) * Kd + gchunk * 8;
    half_t* lA = &As[(wave * 32) * BK];
    half_t* lB = &Bs[(wave * 32) * BK];

    int r = lane & 15;
    int rx = r & 7;

    floatx4 acc[4][4];
    #pragma unroll
    for (int i = 0; i < 4; i++)
        #pragma unroll
        for (int j = 0; j < 4; j++) acc[i][j] = (floatx4){0.f, 0.f, 0.f, 0.f};

    for (int k0 = 0; k0 < Kd; k0 += BK) {
        #pragma unroll
        for (int j = 0; j < 4; j++) {
            async_lds16(ga + k0 + (size_t)(j * 8) * lda, lA + (j * 8) * BK);
            async_lds16(gb + k0 + (size_t)(j * 8) * Kd, lB + (j * 8) * BK);
        }
        __syncthreads();
        #pragma unroll
        for (int kk = 0; kk < BK; kk += 32) {
            int phys = (((kk >> 3) + (lane >> 4)) ^ rx) << 3;
            half8 a[4], b[4];
            #pragma unroll
            for (int i = 0; i < 4; i++)
                a[i] = *(const half8*)&As[(wm + i * 16 + r) * BK + phys];
            #pragma unroll
            for (int j = 0; j < 4; j++)
                b[j] = *(const half8*)&Bs[(wn + j * 16 + r) * BK + phys];
            #pragma unroll
            for (int i = 0; i < 4; i++)
                #pragma unroll
                for (int j = 0; j < 4; j++)
                    acc[i][j] = __builtin_amdgcn_mfma_f32_16x16x32_f16(a[i], b[j], acc[i][j], 0, 0, 0);
        }
        __syncthreads();
    }

    int q4 = (lane >> 4) * 4;
    #pragma unroll
    for (int i = 0; i < 4; i++) {
        #pragma unroll
        for (int rr = 0; rr < 4; rr++) {
            int row = row0 + wm + i * 16 + q4 + rr;
            #pragma unroll
            for (int j = 0; j < 4; j++) {
                int col = col0 + wn + j * 16 + (lane & 15);
                if (col < Nreal) Cp[(size_t)row * ldc + col] = f2h(acc[i][j][rr]);
            }
        }
    }
}

// ---------- aggregation + softmax + ReLU + LayerNorm fused (layers 2,3) ----------

__global__ __launch_bounds__(256) void k_agg_ln(
    const half_t* __restrict__ xp, const float* __restrict__ s, const float* __restrict__ d,
    const int* __restrict__ csr_src, const int* __restrict__ rs,
    const float* __restrict__ bias, const float* __restrict__ gam,
    const float* __restrict__ bet, half_t* __restrict__ outh, int H, int C) {
    __shared__ int sh_src[256];
    __shared__ float sh_w[256 * HH];
    __shared__ float sh_d[HH];
    __shared__ float sh_z[HH];
    __shared__ float red[256];
    __shared__ float red2[256];
    int n = blockIdx.x, tid = threadIdx.x;
    int Dout = H * C;
    int NCH = Dout >> 3;
    int CCH = C >> 3;
    int start = rs[n], end = rs[n + 1];
    if (tid < H) { sh_d[tid] = d[(size_t)n * H + tid]; sh_z[tid] = 0.f; }
    float acc[2][8];
    #pragma unroll
    for (int a = 0; a < 2; a++)
        #pragma unroll
        for (int e = 0; e < 8; e++) acc[a][e] = 0.f;

    for (int e0 = start; e0 < end; e0 += 256) {
        int cnt = min(256, end - e0);
        if (tid < cnt) sh_src[tid] = csr_src[e0 + tid];
        __syncthreads();
        for (int i = tid; i < cnt * H; i += 256) {
            int ei = i / H, h = i - ei * H;
            float v = s[(size_t)sh_src[ei] * H + h] + sh_d[h];
            v = (v >= 0.f) ? v : NEGS * v;   // leaky_relu
            sh_w[i] = expf(v);
        }
        __syncthreads();
        if (tid < H) {
            float zz = 0.f;
            for (int i = 0; i < cnt; i++) zz += sh_w[i * H + tid];
            sh_z[tid] += zz;
        }
        int ai = 0;
        for (int ch = tid; ch < NCH; ch += 256, ai++) {
            int h = ch / CCH;
            float a0 = acc[ai][0], a1 = acc[ai][1], a2 = acc[ai][2], a3 = acc[ai][3];
            float a4 = acc[ai][4], a5 = acc[ai][5], a6 = acc[ai][6], a7 = acc[ai][7];
            for (int i = 0; i < cnt; i++) {
                float w = sh_w[i * H + h];
                half8 v = *(const half8*)(xp + (size_t)sh_src[i] * Dout + (ch << 3));
                a0 += w * (float)v[0]; a1 += w * (float)v[1];
                a2 += w * (float)v[2]; a3 += w * (float)v[3];
                a4 += w * (float)v[4]; a5 += w * (float)v[5];
                a6 += w * (float)v[6]; a7 += w * (float)v[7];
            }
            acc[ai][0] = a0; acc[ai][1] = a1; acc[ai][2] = a2; acc[ai][3] = a3;
            acc[ai][4] = a4; acc[ai][5] = a5; acc[ai][6] = a6; acc[ai][7] = a7;
        }
        __syncthreads();
    }

    float vals[2][8];
    float sum = 0.f, sumsq = 0.f;
    int ai = 0;
    for (int ch = tid; ch < NCH; ch += 256, ai++) {
        int h = ch / CCH;
        float zi = 1.f / (sh_z[h] + 1e-16f);
        #pragma unroll
        for (int e = 0; e < 8; e++) {
            float v = acc[ai][e] * zi + bias[(ch << 3) + e];
            v = fmaxf(v, 0.f);
            vals[ai][e] = v;
            sum += v; sumsq += v * v;
        }
    }
    red[tid] = sum; red2[tid] = sumsq;
    __syncthreads();
    for (int o = 128; o > 0; o >>= 1) {
        if (tid < o) { red[tid] += red[tid + o]; red2[tid] += red2[tid + o]; }
        __syncthreads();
    }
    float mu = red[0] / Dout;
    float var = red2[0] / Dout - mu * mu;
    float rstd = rsqrtf(var + LNEPS);
    ai = 0;
    for (int ch = tid; ch < NCH; ch += 256, ai++) {
        half8 o;
        #pragma unroll
        for (int e = 0; e < 8; e++)
            o[e] = f2h((vals[ai][e] - mu) * rstd * gam[(ch << 3) + e] + bet[(ch << 3) + e]);
        *(half8*)(outh + (size_t)n * Dout + (ch << 3)) = o;
    }
}

// ---------- head aggregation (fused softmax), writes per_head and scattered full ----------

__global__ __launch_bounds__(256) void k_agg_head(
    const half_t* __restrict__ xp, const float* __restrict__ s, const float* __restrict__ d,
    const int* __restrict__ csr_src, const int* __restrict__ rs,
    const float* __restrict__ bias, const int* __restrict__ idxm,
    float* out_full, float* out_ph) {
    __shared__ int sh_src[256];
    __shared__ float sh_w[256 * KK];
    __shared__ float sh_d[KK];
    __shared__ float sh_z[KK];
    int n = blockIdx.x, tid = threadIdx.x;
    const int Dout = KK * MM;        // 2000
    const int NCH = Dout >> 3;       // 250 chunks; threads 250..255 idle
    int start = rs[n], end = rs[n + 1];
    if (tid < KK) { sh_d[tid] = d[(size_t)n * KK + tid]; sh_z[tid] = 0.f; }
    float acc[8];
    #pragma unroll
    for (int e = 0; e < 8; e++) acc[e] = 0.f;
    int ch = tid;
    int cb = ch << 3;

    for (int e0 = start; e0 < end; e0 += 256) {
        int cnt = min(256, end - e0);
        if (tid < cnt) sh_src[tid] = csr_src[e0 + tid];
        __syncthreads();
        for (int i = tid; i < cnt * KK; i += 256) {
            int ei = i / KK, k = i - ei * KK;
            float v = s[(size_t)sh_src[ei] * KK + k] + sh_d[k];
            v = (v >= 0.f) ? v : NEGS * v;
            sh_w[i] = expf(v);
        }
        __syncthreads();
        if (tid < KK) {
            float zz = 0.f;
            for (int i = 0; i < cnt; i++) zz += sh_w[i * KK + tid];
            sh_z[tid] += zz;
        }
        if (ch < NCH) {
            for (int i = 0; i < cnt; i++) {
                const float* wv = &sh_w[i * KK];
                half8 v = *(const half8*)(xp + (size_t)sh_src[i] * Dout + cb);
                #pragma unroll
                for (int e = 0; e < 8; e++)
                    acc[e] += wv[(cb + e) / MM] * (float)v[e];
            }
        }
        __syncthreads();
    }
    if (ch < NCH) {
        #pragma unroll
        for (int e = 0; e < 8; e++) {
            int c = cb + e;
            int k = c / MM, m = c - k * MM;
            float v = acc[e] / (sh_z[k] + 1e-16f) + bias[c];
            out_ph[((size_t)k * NN + n) * MM + m] = v;
            out_full[(size_t)n * GG + idxm[c]] = v;
        }
    }
}

// ---------- host launcher ----------

extern "C" void kernel_launch(void* const* d_in, const int* in_sizes, int n_in,
                              void* d_out, int out_size, void* d_ws, size_t ws_size,
                              hipStream_t stream) {
    (void)in_sizes; (void)n_in; (void)out_size; (void)ws_size;
    const float* x   = (const float*)d_in[0];
    const int*   ei  = (const int*)d_in[1];
    const float* W1  = (const float*)d_in[2];
    const float* as1 = (const float*)d_in[3];
    const float* ad1 = (const float*)d_in[4];
    const float* b1  = (const float*)d_in[5];
    const float* g1  = (const float*)d_in[6];
    const float* be1 = (const float*)d_in[7];
    const float* W2  = (const float*)d_in[8];
    const float* as2 = (const float*)d_in[9];
    const float* ad2 = (const float*)d_in[10];
    const float* b2  = (const float*)d_in[11];
    const float* g2  = (const float*)d_in[12];
    const float* be2 = (const float*)d_in[13];
    const float* W3  = (const float*)d_in[14];
    const float* as3 = (const float*)d_in[15];
    const float* ad3 = (const float*)d_in[16];
    const float* b3  = (const float*)d_in[17];
    const float* g3  = (const float*)d_in[18];
    const float* be3 = (const float*)d_in[19];
    const float* Wh  = (const float*)d_in[20];
    const float* ash = (const float*)d_in[21];
    const float* adh = (const float*)d_in[22];
    const float* bh  = (const float*)d_in[23];
    const int*   idxm = (const int*)d_in[24];
    float* out = (float*)d_out;

    // workspace carve (~54 MB)
    char* w = (char*)d_ws;
    auto carve = [&](size_t bytes) { char* p = w; w += (bytes + 255) & ~(size_t)255; return p; };
    half_t* xp16    = (half_t*)carve((size_t)NN * 3584 * 2);           // GEMM output (fp16)
    half_t* Wt      = (half_t*)carve((size_t)12100000 * 2);            // fp16 weights, two regions
    float*  sarr    = (float*)carve((size_t)NN * HH * 4);
    float*  darr    = (float*)carve((size_t)NN * HH * 4);
    float*  was     = (float*)carve((size_t)HH * 256 * 4);
    float*  wad     = (float*)carve((size_t)HH * 256 * 4);
    int*    csr_src = (int*)carve((size_t)ETOT * 4);
    int*    rowst   = (int*)carve((size_t)(NN + 1) * 4);
    int*    cur     = (int*)carve((size_t)NN * 4);
    half_t* Ah   = (half_t*)d_out;
    half_t* aggx = (half_t*)(out + (size_t)NN * GG);
    half_t* Wt2  = Wt + (size_t)1048576;     // second weight region

    // ---- CSR build + layer-1 prep (fused) ----
    hipMemsetAsync(cur, 0, (size_t)NN * 4, stream);
    k_count<<<(ETOT + 255) / 256, 256, 0, stream>>>(ei, cur);
    k_scan<<<1, 1024, 0, stream>>>(cur, rowst, NN);          // also re-zeroes cur
    k_wa_wt1<<<NWA + WT1X * 8, 256, 0, stream>>>(W1, as1, ad1, was, wad, Wt);
    k_fill_f2h_sdx<<<2048, 256, 0, stream>>>(
        ei, rowst, cur, csr_src, (const floatx4*)x, (half4*)Ah,
        x, was, wad, sarr, darr);

    // ---- layer 1 (input-space aggregation) ----
    k_agg_x<<<NN, 256, 0, stream>>>(Ah, sarr, darr, csr_src, rowst, aggx);
    k_gemm_mfma<<<dim3(4, NN / BM, HH), 256, 0, stream>>>(
        aggx, Wt, xp16, 256, HH * 256, 448, 3584,
        256LL, (long long)448 * 256, 448LL);
    k_ln_wt2<<<NN + WT2X * 112, 256, 0, stream>>>(xp16, b1, g1, be1, Ah, W2, Wt2);

    // ---- layer 2 ----
    k_gemm_mfma<<<dim3(3072 / BN, NN / BM, 1), 256, 0, stream>>>(
        Ah, Wt2, xp16, 3584, 3584, 3072, 3072, 0, 0, 0);
    k_sd_wt<<<8192 + 6144, 256, 0, stream>>>(
        xp16, as2, ad2, sarr, darr, HH, 384, 8192, NN * HH,
        W3, Wt, 3072, 2048, 2048, 0, 0, 64, 96);
    k_agg_ln<<<NN, 256, 0, stream>>>(xp16, sarr, darr, csr_src, rowst,
                                     b2, g2, be2, Ah, HH, 384);

    // ---- layer 3 ----
    k_gemm_mfma<<<dim3(2048 / BN, NN / BM, 1), 256, 0, stream>>>(
        Ah, Wt, xp16, 3072, 3072, 2048, 2048, 0, 0, 0);
    k_sd_wt<<<8192 + 4096, 256, 0, stream>>>(
        xp16, as3, ad3, sarr, darr, HH, 256, 8192, NN * HH,
        Wh, Wt, 2048, MM, MM, (long long)2048 * MM, (long long)512 * 2048, 16, 64);
    k_agg_ln<<<NN, 256, 0, stream>>>(xp16, sarr, darr, csr_src, rowst,
                                     b3, g3, be3, Ah, HH, 256);

    // ---- head stage ----
    k_gemm_mfma<<<dim3(512 / BN, NN / BM, KK), 256, 0, stream>>>(
        Ah, Wt, xp16, 2048, 2048, MM, GG, 0, (long long)512 * 2048, (long long)MM);
    k_sd4<<<(NN * KK) / 4, 256, 0, stream>>>(xp16, ash, adh, sarr, darr, KK, MM, NN * KK);
    k_agg_head<<<NN, 256, 0, stream>>>(xp16, sarr, darr, csr_src, rowst,
                                       bh, idxm, out, out + (size_t)NN * GG);
}